// Round 11
// baseline (196.964 us; speedup 1.0000x reference)
//
#include <hip/hip_runtime.h>
#include <hip/hip_bf16.h>

typedef __hip_bfloat16 bf16;
typedef short v8s __attribute__((ext_vector_type(8)));
typedef float v4f __attribute__((ext_vector_type(4)));
typedef float v16f __attribute__((ext_vector_type(16)));

#define S_ 2048
#define D_ 1024
#define H_ 16
#define HD_ 64

#define EXP2F(x) __builtin_amdgcn_exp2f(x)   /* v_exp_f32: 2^x on gfx950 */
#define NEG_BIG (-1.0e30f)
#define C2 0.1803368801111244f   /* (1/sqrt(64)) * log2(e), folded into Q */

#define GLDS16(g, l) __builtin_amdgcn_global_load_lds(                        \
    (const __attribute__((address_space(1))) unsigned int*)(g),               \
    (__attribute__((address_space(3))) unsigned int*)(l), 16, 0, 0)

#define CVT_PK(d, lo, hi) \
    asm("v_cvt_pk_bf16_f32 %0, %1, %2" : "=v"(d) : "v"(lo), "v"(hi))

/* exchanges high 32 lanes of a with low 32 lanes of b (gfx950) */
#define SWAPHALF(a, b) \
    asm("v_permlane32_swap_b32 %0, %1" : "+v"(a), "+v"(b))

#define MFMA32(a, b, c) __builtin_amdgcn_mfma_f32_32x32x16_bf16(a, b, c, 0, 0, 0)

static __device__ __forceinline__ unsigned short bf16_bits(bf16 h) {
    union { bf16 h; unsigned short u; } c; c.h = h; return c.u;
}

static __device__ __forceinline__ v8s pack_bf16x8(const float4 a, const float4 b) {
    union { v8s v; unsigned short u[8]; } r;
    r.u[0] = bf16_bits(__float2bfloat16(a.x));
    r.u[1] = bf16_bits(__float2bfloat16(a.y));
    r.u[2] = bf16_bits(__float2bfloat16(a.z));
    r.u[3] = bf16_bits(__float2bfloat16(a.w));
    r.u[4] = bf16_bits(__float2bfloat16(b.x));
    r.u[5] = bf16_bits(__float2bfloat16(b.y));
    r.u[6] = bf16_bits(__float2bfloat16(b.z));
    r.u[7] = bf16_bits(__float2bfloat16(b.w));
    return r.v;
}

// ---------------------------------------------------------------------------
// fp32 -> bf16 conversion pre-pass
// ---------------------------------------------------------------------------
__global__ __launch_bounds__(256)
void cvt_bf16(const float* __restrict__ x,  const float* __restrict__ wq,
              const float* __restrict__ wk, const float* __restrict__ wv,
              const float* __restrict__ wo,
              bf16* __restrict__ xb,  bf16* __restrict__ wqb,
              bf16* __restrict__ wkb, bf16* __restrict__ wvb,
              bf16* __restrict__ wob)
{
    const int seg = blockIdx.y;
    const float* src; bf16* dst; int n;
    switch (seg) {
        case 0: src = x;  dst = xb;  n = 4096 * 1024; break;
        case 1: src = wq; dst = wqb; n = 1024 * 1024; break;
        case 2: src = wk; dst = wkb; n = 1024 * 1024; break;
        case 3: src = wv; dst = wvb; n = 1024 * 1024; break;
        default:src = wo; dst = wob; n = 1024 * 1024; break;
    }
    const int idx = (blockIdx.x * 256 + threadIdx.x) * 8;
    if (idx >= n) return;
    *(v8s*)&dst[idx] = pack_bf16x8(*(const float4*)&src[idx],
                                   *(const float4*)&src[idx + 4]);
}

// ---------------------------------------------------------------------------
// QKV GEMM, 256x256 8-phase schedule (T3+T4+T5) + T2 XOR-swizzled LDS.
// (Verified round 4: T2 on the 8-phase structure gave ~-11us vs linear LDS.)
// ---------------------------------------------------------------------------
static __device__ __forceinline__ void stage_half(bf16* ldsbase, const bf16* gbase,
                                                  int w, int l) {
    const int r = l >> 3, c = ((l & 7) ^ r) * 8;  // T2 inverse-swizzled source
    GLDS16(gbase + (size_t)((2 * w + 0) * 8 + r) * 1024 + c, ldsbase + (2 * w + 0) * 512);
    GLDS16(gbase + (size_t)((2 * w + 1) * 8 + r) * 1024 + c, ldsbase + (2 * w + 1) * 512);
}

#define MF16(a, b, c) __builtin_amdgcn_mfma_f32_16x16x32_bf16(a, b, c, 0, 0, 0)

#define LDA(buf, mf0) { _Pragma("unroll") for (int m_ = 0; m_ < 4; ++m_) {          \
    af[m_][0] = *(const v8s*)&AsS[(buf)*16384 + abase + ((mf0) + m_)*1024 + sw0];   \
    af[m_][1] = *(const v8s*)&AsS[(buf)*16384 + abase + ((mf0) + m_)*1024 + sw1]; } }
#define LDB0(buf) { _Pragma("unroll") for (int n_ = 0; n_ < 2; ++n_) {              \
    b0f[n_][0] = *(const v8s*)&BsS[(buf)*16384 + bbase + n_*1024 + sw0];            \
    b0f[n_][1] = *(const v8s*)&BsS[(buf)*16384 + bbase + n_*1024 + sw1]; } }
#define LDB1(buf) { _Pragma("unroll") for (int n_ = 0; n_ < 2; ++n_) {              \
    b1f[n_][0] = *(const v8s*)&BsS[(buf)*16384 + bbase + (2 + n_)*1024 + sw0];      \
    b1f[n_][1] = *(const v8s*)&BsS[(buf)*16384 + bbase + (2 + n_)*1024 + sw1]; } }
#define MMQ(MH, NH, AF, BF) { _Pragma("unroll") for (int m_ = 0; m_ < 4; ++m_)      \
    _Pragma("unroll") for (int n_ = 0; n_ < 2; ++n_) {                              \
      acc[(MH)*4 + m_][(NH)*2 + n_] =                                               \
        MF16(AF[m_][0], BF[n_][0], acc[(MH)*4 + m_][(NH)*2 + n_]);                  \
      acc[(MH)*4 + m_][(NH)*2 + n_] =                                               \
        MF16(AF[m_][1], BF[n_][1], acc[(MH)*4 + m_][(NH)*2 + n_]); } }
#define BAR() __builtin_amdgcn_s_barrier()
#define VMC2() asm volatile("s_waitcnt vmcnt(2)" ::: "memory")
#define PRIO1() __builtin_amdgcn_s_setprio(1)
#define PRIO0() __builtin_amdgcn_s_setprio(0)

__global__ __launch_bounds__(512, 2)
void gemm_qkv_8p(const bf16* __restrict__ xb, const bf16* __restrict__ wqb,
                 const bf16* __restrict__ wkb, const bf16* __restrict__ wvb,
                 bf16* __restrict__ qd, bf16* __restrict__ kd, bf16* __restrict__ vtd)
{
    __shared__ bf16 AsS[2 * 16384];          // [buf][half 128][64]
    __shared__ bf16 BsS[2 * 16384];
    const int mode = blockIdx.z;
    const bf16* __restrict__ W = (mode == 0) ? wqb : (mode == 1) ? wkb : wvb;
    const int m0 = blockIdx.x * 256;
    const int n0 = blockIdx.y * 256;
    const int t = threadIdx.x;
    const int lane = t & 63, w = t >> 6;
    const int wr = w >> 2, wc = w & 3;       // 2M x 4N waves
    const int l15 = lane & 15, quad = lane >> 4;
    const int sw0 = (quad ^ (l15 & 7)) * 8;          // T2 swizzled col-slots
    const int sw1 = ((quad + 4) ^ (l15 & 7)) * 8;
    const int abase = wr * 8192 + l15 * 64;
    const int bbase = (wc >> 1) * 8192 + (wc & 1) * 4096 + l15 * 64;
    const bf16* Aap = xb + (size_t)m0 * 1024;
    const bf16* Bbp = W + (size_t)n0 * 1024;

    v4f acc[8][4] = {};
    v8s af[4][2], b0f[2][2], b1f[2][2];

    // prologue: tile0 (buf0, 4 halves) + tile1 A0 (buf1); keep tile1-A0 in flight
    stage_half(AsS,          Aap,          w, lane);
    stage_half(AsS + 8192,   Aap + 131072, w, lane);
    stage_half(BsS,          Bbp,          w, lane);
    stage_half(BsS + 8192,   Bbp + 131072, w, lane);
    stage_half(AsS + 16384,  Aap + 64,     w, lane);
    VMC2();
    BAR();

    for (int i = 0; i < 8; ++i) {
        const int kc = i * 128;
        // ph1: buf0 A-mh0 + B-nh0; stage tile(2i+1) A1 -> buf1
        LDA(0, 0); LDB0(0);
        stage_half(AsS + 16384 + 8192, Aap + 131072 + kc + 64, w, lane);
        BAR(); PRIO1(); MMQ(0, 0, af, b0f); PRIO0(); BAR();
        // ph2: buf0 B-nh1; stage tile(2i+1) B0 -> buf1
        LDB1(0);
        stage_half(BsS + 16384, Bbp + kc + 64, w, lane);
        BAR(); PRIO1(); MMQ(0, 1, af, b1f); PRIO0(); BAR();
        // ph3: buf0 A-mh1; stage tile(2i+1) B1 -> buf1
        LDA(0, 4);
        stage_half(BsS + 16384 + 8192, Bbp + 131072 + kc + 64, w, lane);
        BAR(); PRIO1(); MMQ(1, 1, af, b1f); PRIO0(); BAR();
        // ph4: stage tile(2i+2) A0 -> buf0; counted wait for tile(2i+1)
        stage_half(AsS, Aap + kc + 128, w, lane);
        VMC2();
        BAR(); PRIO1(); MMQ(1, 0, af, b0f); PRIO0(); BAR();
        // ph5: buf1 A-mh0 + B-nh0; stage tile(2i+2) A1 -> buf0
        LDA(1, 0); LDB0(1);
        stage_half(AsS + 8192, Aap + 131072 + kc + 128, w, lane);
        BAR(); PRIO1(); MMQ(0, 0, af, b0f); PRIO0(); BAR();
        // ph6: buf1 B-nh1; stage tile(2i+2) B0 -> buf0
        LDB1(1);
        stage_half(BsS, Bbp + kc + 128, w, lane);
        BAR(); PRIO1(); MMQ(0, 1, af, b1f); PRIO0(); BAR();
        // ph7: buf1 A-mh1; stage tile(2i+2) B1 -> buf0
        LDA(1, 4);
        stage_half(BsS + 8192, Bbp + 131072 + kc + 128, w, lane);
        BAR(); PRIO1(); MMQ(1, 1, af, b1f); PRIO0(); BAR();
        // ph8: stage tile(2i+3) A0 -> buf1; counted wait for tile(2i+2)
        stage_half(AsS + 16384, Aap + kc + 192, w, lane);
        VMC2();
        BAR(); PRIO1(); MMQ(1, 0, af, b0f); PRIO0(); BAR();
    }

    const float qscale = (mode == 0) ? C2 : 1.0f;
#pragma unroll
    for (int mf = 0; mf < 8; ++mf) {
        const int mb = m0 + wr * 128 + mf * 16 + quad * 4;
        const int b_ = mb >> 11, s = mb & 2047;
#pragma unroll
        for (int nf = 0; nf < 4; ++nf) {
            const int n = n0 + wc * 64 + nf * 16 + l15;
            const int h = n >> 6, d = n & 63;
            if (mode == 2) {
                unsigned int lo = (unsigned int)bf16_bits(__float2bfloat16(acc[mf][nf][0]))
                                | ((unsigned int)bf16_bits(__float2bfloat16(acc[mf][nf][1])) << 16);
                unsigned int hi = (unsigned int)bf16_bits(__float2bfloat16(acc[mf][nf][2]))
                                | ((unsigned int)bf16_bits(__float2bfloat16(acc[mf][nf][3])) << 16);
                uint2 pv; pv.x = lo; pv.y = hi;
                *(uint2*)&vtd[((b_ * H_ + h) * HD_ + d) * S_ + s] = pv;
            } else {
                bf16* __restrict__ dst = (mode == 0) ? qd : kd;
#pragma unroll
                for (int r = 0; r < 4; ++r)
                    dst[((b_ * H_ + h) * S_ + (s + r)) * HD_ + d] =
                        __float2bfloat16(acc[mf][nf][r] * qscale);
            }
        }
    }
}

// ---------------------------------------------------------------------------
// Output GEMM (m97-style 128x128): 256 blocks keeps all CUs busy at N=1024.
// ---------------------------------------------------------------------------
__global__ __launch_bounds__(256)
void gemm_out_f(const bf16* __restrict__ ctx, const bf16* __restrict__ wob,
                const float* __restrict__ bo, float* __restrict__ out)
{
    const int m0 = blockIdx.x * 128;
    const int n0 = blockIdx.y * 128;
    __shared__ bf16 As[128 * 32];
    __shared__ bf16 Bs[128 * 32];
    const int t    = threadIdx.x;
    const int lane = t & 63, w = t >> 6;
    const int wr = w >> 1, wc = w & 1;
    const int l15 = lane & 15, quad = lane >> 4;
    const int r16 = lane >> 2, c8 = (lane & 3) * 8;
    v4f acc[4][4] = {};

    const bf16* ga = &ctx[(m0 + w*16 + r16) * 1024 + c8];
    const bf16* gb = &wob[(n0 + w*16 + r16) * 1024 + c8];
    bf16* la0 = &As[w * 16 * 32];
    bf16* la1 = &As[(64 + w * 16) * 32];
    bf16* lb0 = &Bs[w * 16 * 32];
    bf16* lb1 = &Bs[(64 + w * 16) * 32];

    for (int k0 = 0; k0 < 1024; k0 += 32) {
        __syncthreads();
        GLDS16(ga + k0,             la0);
        GLDS16(ga + k0 + 64 * 1024, la1);
        GLDS16(gb + k0,             lb0);
        GLDS16(gb + k0 + 64 * 1024, lb1);
        __syncthreads();
        v8s a[4], b[4];
#pragma unroll
        for (int mt = 0; mt < 4; mt++) a[mt] = *(const v8s*)&As[(wr*64 + mt*16 + l15)*32 + quad*8];
#pragma unroll
        for (int nt = 0; nt < 4; nt++) b[nt] = *(const v8s*)&Bs[(wc*64 + nt*16 + l15)*32 + quad*8];
#pragma unroll
        for (int mt = 0; mt < 4; mt++)
#pragma unroll
            for (int nt = 0; nt < 4; nt++)
                acc[mt][nt] = __builtin_amdgcn_mfma_f32_16x16x32_bf16(a[mt], b[nt], acc[mt][nt], 0, 0, 0);
    }

#pragma unroll
    for (int mt = 0; mt < 4; mt++) {
        const int mb = m0 + wr*64 + mt*16 + quad*4;
#pragma unroll
        for (int nt = 0; nt < 4; nt++) {
            const int n = n0 + wc*64 + nt*16 + l15;
            const float bias = bo[n];
#pragma unroll
            for (int r = 0; r < 4; r++)
                out[(mb + r)*1024 + n] = acc[mt][nt][r] + bias;
        }
    }
}

// ---------------------------------------------------------------------------
// FALLBACK GEMMs (fp32 inputs, cvt fused in staging)
// ---------------------------------------------------------------------------
__global__ __launch_bounds__(256)
void gemm_qkv(const float* __restrict__ x, const float* __restrict__ Wq,
              const float* __restrict__ Wk, const float* __restrict__ Wv,
              bf16* __restrict__ qd, bf16* __restrict__ kd, bf16* __restrict__ vtd)
{
    const int mode = blockIdx.z;
    const float* __restrict__ W = (mode == 0) ? Wq : (mode == 1) ? Wk : Wv;
    const int m0 = blockIdx.x * 128;
    const int n0 = blockIdx.y * 128;
    __shared__ bf16 As[128 * 40];
    __shared__ bf16 Bs[128 * 40];
    const int t    = threadIdx.x;
    const int lane = t & 63, w = t >> 6;
    const int wr = w >> 1, wc = w & 1;
    const int l15 = lane & 15, quad = lane >> 4;
    const int srow = t >> 2, scol = (t & 3) * 8;
    v4f acc[4][4] = {};

    for (int k0 = 0; k0 < 1024; k0 += 32) {
        __syncthreads();
        {
            const float* pa = &x[(m0 + srow) * 1024 + k0 + scol];
            *(v8s*)&As[srow*40 + scol] = pack_bf16x8(*(const float4*)pa, *(const float4*)(pa + 4));
            const float* pa2 = pa + 64 * 1024;
            *(v8s*)&As[(srow+64)*40 + scol] = pack_bf16x8(*(const float4*)pa2, *(const float4*)(pa2 + 4));
            const float* pb = &W[(n0 + srow) * 1024 + k0 + scol];
            *(v8s*)&Bs[srow*40 + scol] = pack_bf16x8(*(const float4*)pb, *(const float4*)(pb + 4));
            const float* pb2 = pb + 64 * 1024;
            *(v8s*)&Bs[(srow+64)*40 + scol] = pack_bf16x8(*(const float4*)pb2, *(const float4*)(pb2 + 4));
        }
        __syncthreads();
        v8s a[4], b[4];
#pragma unroll
        for (int mt = 0; mt < 4; mt++) a[mt] = *(const v8s*)&As[(wr*64 + mt*16 + l15)*40 + quad*8];
#pragma unroll
        for (int nt = 0; nt < 4; nt++) b[nt] = *(const v8s*)&Bs[(wc*64 + nt*16 + l15)*40 + quad*8];
#pragma unroll
        for (int mt = 0; mt < 4; mt++)
#pragma unroll
            for (int nt = 0; nt < 4; nt++)
                acc[mt][nt] = __builtin_amdgcn_mfma_f32_16x16x32_bf16(a[mt], b[nt], acc[mt][nt], 0, 0, 0);
    }

    const float qscale = (mode == 0) ? C2 : 1.0f;
#pragma unroll
    for (int mt = 0; mt < 4; mt++) {
        const int mb = m0 + wr*64 + mt*16 + quad*4;
        const int b_ = mb >> 11, s = mb & 2047;
#pragma unroll
        for (int nt = 0; nt < 4; nt++) {
            const int n = n0 + wc*64 + nt*16 + l15;
            const int h = n >> 6, d = n & 63;
            if (mode == 2) {
                unsigned int lo = (unsigned int)bf16_bits(__float2bfloat16(acc[mt][nt][0]))
                                | ((unsigned int)bf16_bits(__float2bfloat16(acc[mt][nt][1])) << 16);
                unsigned int hi = (unsigned int)bf16_bits(__float2bfloat16(acc[mt][nt][2]))
                                | ((unsigned int)bf16_bits(__float2bfloat16(acc[mt][nt][3])) << 16);
                uint2 pv; pv.x = lo; pv.y = hi;
                *(uint2*)&vtd[((b_*H_ + h)*HD_ + d)*S_ + s] = pv;
            } else {
                bf16* __restrict__ dst = (mode == 0) ? qd : kd;
#pragma unroll
                for (int r = 0; r < 4; r++)
                    dst[((b_*H_ + h)*S_ + (s + r))*HD_ + d] = __float2bfloat16(acc[mt][nt][r] * qscale);
            }
        }
    }
}

__global__ __launch_bounds__(256)
void gemm_out(const bf16* __restrict__ ctx, const float* __restrict__ Wo,
              const float* __restrict__ bo, float* __restrict__ out)
{
    const int m0 = blockIdx.x * 128;
    const int n0 = blockIdx.y * 128;
    __shared__ bf16 As[128 * 40];
    __shared__ bf16 Bs[128 * 40];
    const int t    = threadIdx.x;
    const int lane = t & 63, w = t >> 6;
    const int wr = w >> 1, wc = w & 1;
    const int l15 = lane & 15, quad = lane >> 4;
    const int srow = t >> 2, scol = (t & 3) * 8;
    v4f acc[4][4] = {};

    for (int k0 = 0; k0 < 1024; k0 += 32) {
        __syncthreads();
        {
            *(v8s*)&As[srow*40 + scol]      = *(const v8s*)&ctx[(m0+srow)*1024 + k0 + scol];
            *(v8s*)&As[(srow+64)*40 + scol] = *(const v8s*)&ctx[(m0+srow+64)*1024 + k0 + scol];
            const float* pb = &Wo[(n0 + srow) * 1024 + k0 + scol];
            *(v8s*)&Bs[srow*40 + scol] = pack_bf16x8(*(const float4*)pb, *(const float4*)(pb + 4));
            const float* pb2 = pb + 64 * 1024;
            *(v8s*)&Bs[(srow+64)*40 + scol] = pack_bf16x8(*(const float4*)pb2, *(const float4*)(pb2 + 4));
        }
        __syncthreads();
        v8s a[4], b[4];
#pragma unroll
        for (int mt = 0; mt < 4; mt++) a[mt] = *(const v8s*)&As[(wr*64 + mt*16 + l15)*40 + quad*8];
#pragma unroll
        for (int nt = 0; nt < 4; nt++) b[nt] = *(const v8s*)&Bs[(wc*64 + nt*16 + l15)*40 + quad*8];
#pragma unroll
        for (int mt = 0; mt < 4; mt++)
#pragma unroll
            for (int nt = 0; nt < 4; nt++)
                acc[mt][nt] = __builtin_amdgcn_mfma_f32_16x16x32_bf16(a[mt], b[nt], acc[mt][nt], 0, 0, 0);
    }

#pragma unroll
    for (int mt = 0; mt < 4; mt++) {
        const int mb = m0 + wr*64 + mt*16 + quad*4;
#pragma unroll
        for (int nt = 0; nt < 4; nt++) {
            const int n = n0 + wc*64 + nt*16 + l15;
            const float bias = bo[n];
#pragma unroll
            for (int r = 0; r < 4; r++)
                out[(mb + r)*1024 + n] = acc[mt][nt][r] + bias;
        }
    }
}

// ---------------------------------------------------------------------------
// Causal flash attention v13 = v11 datapath, UN-PAIRED into independent
// 4-wave blocks (barrier decoupling):
//  * Grid 32 bh x 16 q-tiles = 512 blocks of 256 threads (4 waves), each
//    block owns ONE q-tile (128 rows; wave wl -> 32 rows), nT = pt+1
//    128-wide kv tiles, longest tiles dispatched first (dynamic refill).
//  * 2 blocks/CU co-resident (LDS 34.8KB) = same 8 waves/CU as v11, but in
//    TWO INDEPENDENT barrier domains: when one block drains at its barrier
//    the other block's waves issue — v11's single 512-thread block stalled
//    the whole CU at every __syncthreads.
//  * Per-wave code identical to verified v11: swapped QK^T (mfma32(K,Q)),
//    T12 in-register softmax (cvt_pk + permlane32_swap), K-from-global
//    consume-then-prefetch chain, V LDS double-buffer (1 barrier/tile).
//  * Plain __launch_bounds__(256) — no min-blocks arg (R7/R8 lesson).
// ---------------------------------------------------------------------------
#define SOFTMAX_PV(sa, ks0, vA0, vA1, vB0, vB1)                                \
    {                                                                          \
        const bool full_ = ((ks0) + 31 <= q0w);                                \
        if (full_) {                                                           \
            _Pragma("unroll")                                                  \
            for (int r = 0; r < 16; r++) {                                     \
                const float p = EXP2F(sa[r]); sa[r] = p;                       \
                if (r & 1) ps1 += p; else ps0 += p;                            \
            }                                                                  \
        } else {                                                               \
            const int kb_ = (ks0) + 4 * hi - q0w - l31;                        \
            _Pragma("unroll")                                                  \
            for (int r = 0; r < 16; r++) {                                     \
                const int kl_ = (r & 3) + 8 * (r >> 2);                        \
                const float p = EXP2F((kb_ + kl_ <= 0) ? sa[r] : NEG_BIG);     \
                sa[r] = p;                                                     \
                if (r & 1) ps1 += p; else ps0 += p;                            \
            }                                                                  \
        }                                                                      \
        unsigned u0, u1, u2, u3, u4, u5, u6, u7;                               \
        CVT_PK(u0, sa[0],  sa[1]);  CVT_PK(u1, sa[2],  sa[3]);                 \
        CVT_PK(u2, sa[4],  sa[5]);  CVT_PK(u3, sa[6],  sa[7]);                 \
        CVT_PK(u4, sa[8],  sa[9]);  CVT_PK(u5, sa[10], sa[11]);                \
        CVT_PK(u6, sa[12], sa[13]); CVT_PK(u7, sa[14], sa[15]);                \
        SWAPHALF(u0, u2); SWAPHALF(u1, u3);                                    \
        SWAPHALF(u4, u6); SWAPHALF(u5, u7);                                    \
        union { v8s v; unsigned w[4]; } pa0_, pa1_;                            \
        pa0_.w[0] = u0; pa0_.w[1] = u1; pa0_.w[2] = u2; pa0_.w[3] = u3;        \
        pa1_.w[0] = u4; pa1_.w[1] = u5; pa1_.w[2] = u6; pa1_.w[3] = u7;        \
        o0 = MFMA32(pa0_.v, vA0, o0);                                          \
        o1 = MFMA32(pa0_.v, vB0, o1);                                          \
        o0 = MFMA32(pa1_.v, vA1, o0);                                          \
        o1 = MFMA32(pa1_.v, vB1, o1);                                          \
    }

__global__ __launch_bounds__(256)
void flash_attn(const bf16* __restrict__ qd, const bf16* __restrict__ kd,
                const bf16* __restrict__ vtd, bf16* __restrict__ ctx)
{
    const int bh = blockIdx.x;            // 0..31 — same bh => same XCD
    const int pt = 15 - (int)blockIdx.y;  // q-tile, longest first
    const int t = threadIdx.x;            // 0..255
    const int lane = t & 63, wl = t >> 6; // 4 waves
    const int l31 = lane & 31, hi = lane >> 5;
    const int q0w = pt * 128 + wl * 32;   // wave's 32 q-rows
    const int nT = pt + 1;                // 128-wide kv tiles

    __shared__ bf16 Vs[2][64 * 136];      // [d][kv 128 + 8 pad]

    // Q B-frags (col=q=l31, k-elem=d=hi*8+j+16*c), resident whole kernel
    const bf16* qp = qd + ((size_t)bh * S_ + q0w + l31) * HD_ + hi * 8;
    const v8s qf0 = *(const v8s*)(qp);
    const v8s qf1 = *(const v8s*)(qp + 16);
    const v8s qf2 = *(const v8s*)(qp + 32);
    const v8s qf3 = *(const v8s*)(qp + 48);

    v16f o0 = {}, o1 = {};                // d = l31 / l31+32; q via regs
    float ps0 = 0.f, ps1 = 0.f;

    // V staging: 256 thr x 4 v8s. Lanes 0-7 cover one row's 64 cols (128B
    // contiguous -> coalesced + conflict-free, same pattern as v11).
    const int vrow = t >> 3, vcol = (t & 7) * 8;   // rows 0..31 (+32 pair)
    const bf16* vp = vtd + ((size_t)bh * HD_ + vrow) * S_ + vcol;
    v8s pv0 = *(const v8s*)vp;                      // (vrow,    vcol)
    v8s pv1 = *(const v8s*)(vp + 64);               // (vrow,    vcol+64)
    v8s pv2 = *(const v8s*)(vp + 32 * S_);          // (vrow+32, vcol)
    v8s pv3 = *(const v8s*)(vp + 32 * S_ + 64);     // (vrow+32, vcol+64)

    // K A-frags (row=k=l31 (+32 for B-group), k-elem=d), group 0
    const bf16* kq = kd + ((size_t)bh * S_ + l31) * HD_ + hi * 8;
    v8s kA0 = *(const v8s*)(kq);
    v8s kA1 = *(const v8s*)(kq + 16);
    v8s kA2 = *(const v8s*)(kq + 32);
    v8s kA3 = *(const v8s*)(kq + 48);
    v8s kB0 = *(const v8s*)(kq + 32 * HD_);
    v8s kB1 = *(const v8s*)(kq + 32 * HD_ + 16);
    v8s kB2 = *(const v8s*)(kq + 32 * HD_ + 32);
    v8s kB3 = *(const v8s*)(kq + 32 * HD_ + 48);

    for (int it = 0; it < nT; ++it) {
        const int c0 = it * 128;
        bf16* Vb = &Vs[it & 1][0];
        *(v8s*)&Vb[ vrow      *136 + vcol]      = pv0;
        *(v8s*)&Vb[ vrow      *136 + 64 + vcol] = pv1;
        *(v8s*)&Vb[(vrow + 32)*136 + vcol]      = pv2;
        *(v8s*)&Vb[(vrow + 32)*136 + 64 + vcol] = pv3;
        __syncthreads();
        vp += 128;
        pv0 = *(const v8s*)vp;            // prefetch next V tile (overrun in ws)
        pv1 = *(const v8s*)(vp + 64);
        pv2 = *(const v8s*)(vp + 32 * S_);
        pv3 = *(const v8s*)(vp + 32 * S_ + 64);

#pragma unroll
        for (int h = 0; h < 2; ++h) {
            const int ch = c0 + h * 64;
            const bool actA = (ch      <= q0w + 31);
            const bool actB = (ch + 32 <= q0w + 31);
            const bool nact = (ch + 64 <= q0w + 31);

            v16f sa0 = {}, sa1 = {};
            if (actA) {
                sa0 = MFMA32(kA0, qf0, sa0);
                sa0 = MFMA32(kA1, qf1, sa0);
                sa0 = MFMA32(kA2, qf2, sa0);
                sa0 = MFMA32(kA3, qf3, sa0);
            }
            if (actB) {
                sa1 = MFMA32(kB0, qf0, sa1);
                sa1 = MFMA32(kB1, qf1, sa1);
                sa1 = MFMA32(kB2, qf2, sa1);
                sa1 = MFMA32(kB3, qf3, sa1);
            }

            // K consumed -> prefetch next 64-group into the same registers
            if (nact) {
                const bf16* kn = kq + (size_t)(ch + 64) * HD_;
                kA0 = *(const v8s*)(kn);
                kA1 = *(const v8s*)(kn + 16);
                kA2 = *(const v8s*)(kn + 32);
                kA3 = *(const v8s*)(kn + 48);
                kB0 = *(const v8s*)(kn + 32 * HD_);
                kB1 = *(const v8s*)(kn + 32 * HD_ + 16);
                kB2 = *(const v8s*)(kn + 32 * HD_ + 32);
                kB3 = *(const v8s*)(kn + 32 * HD_ + 48);
            }

            if (actA) {
                const int kb = h * 64;
                const v8s vA0 = *(const v8s*)&Vb[ l31      *136 + kb      + hi*8];
                const v8s vA1 = *(const v8s*)&Vb[ l31      *136 + kb + 16 + hi*8];
                const v8s vB0 = *(const v8s*)&Vb[(l31 + 32)*136 + kb      + hi*8];
                const v8s vB1 = *(const v8s*)&Vb[(l31 + 32)*136 + kb + 16 + hi*8];
                SOFTMAX_PV(sa0, ch, vA0, vA1, vB0, vB1);
            }
            if (actB) {
                const int kb = h * 64 + 32;
                const v8s vA2 = *(const v8s*)&Vb[ l31      *136 + kb      + hi*8];
                const v8s vA3 = *(const v8s*)&Vb[ l31      *136 + kb + 16 + hi*8];
                const v8s vB2 = *(const v8s*)&Vb[(l31 + 32)*136 + kb      + hi*8];
                const v8s vB3 = *(const v8s*)&Vb[(l31 + 32)*136 + kb + 16 + hi*8];
                SOFTMAX_PV(sa1, ch + 32, vA2, vA3, vB2, vB3);
            }
        }
    }

    // denominator for q=l31: this lane's half + the other hi half
    const float ps = ps0 + ps1;
    const float tot = ps + __shfl_xor(ps, 32);
    const int b_ = bh >> 4, hh = bh & 15;
    bf16* cb = ctx + ((size_t)b_ * S_ + q0w) * D_ + hh * HD_ + l31;
#pragma unroll
    for (int r = 0; r < 16; r++) {
        const int qr = (r & 3) + 8 * (r >> 2) + 4 * hi;
        const float linv = 1.0f / __shfl(tot, qr);
        cb[(size_t)qr * D_]      = __float2bfloat16(o0[r] * linv);
        cb[(size_t)qr * D_ + 32] = __float2bfloat16(o1[r] * linv);
    }
}

extern "C" void kernel_launch(void* const* d_in, const int* in_sizes, int n_in,
                              void* d_out, int out_size, void* d_ws, size_t ws_size,
                              hipStream_t stream) {
    const float* x  = (const float*)d_in[0];
    const float* Wq = (const float*)d_in[1];
    const float* Wk = (const float*)d_in[2];
    const float* Wv = (const float*)d_in[3];
    const float* Wo = (const float*)d_in[4];
    const float* bo = (const float*)d_in[5];
    float* out = (float*)d_out;

    const size_t SEG = (size_t)2 * H_ * S_ * HD_;      // 4 Mi bf16 elems = 8 MB
    bf16* qd  = (bf16*)d_ws;
    bf16* kd  = qd  + SEG;
    bf16* vtd = kd  + SEG;
    bf16* xc  = vtd + SEG;                             // x-bf16, later ctx
    bf16* wqb = xc + SEG;
    bf16* wkb = wqb + 1024 * 1024;
    bf16* wvb = wkb + 1024 * 1024;
    bf16* wob = wvb + 1024 * 1024;

    const size_t need_fast = (4 * SEG + 4 * 1024 * 1024) * sizeof(bf16);   // 40 MB

    if (ws_size >= need_fast) {
        cvt_bf16<<<dim3(2048, 5), 256, 0, stream>>>(x, Wq, Wk, Wv, Wo,
                                                    xc, wqb, wkb, wvb, wob);
        gemm_qkv_8p<<<dim3(16, 4, 3), 512, 0, stream>>>(xc, wqb, wkb, wvb, qd, kd, vtd);
        flash_attn<<<dim3(32, 16), 256, 0, stream>>>(qd, kd, vtd, xc);   // xc = ctx
        gemm_out_f<<<dim3(32, 8), 256, 0, stream>>>(xc, wob, bo, out);
    } else {
        gemm_qkv<<<dim3(32, 8, 3), 256, 0, stream>>>(x, Wq, Wk, Wv, qd, kd, vtd);
        flash_attn<<<dim3(32, 16), 256, 0, stream>>>(qd, kd, vtd, xc);
        gemm_out<<<dim3(32, 8), 256, 0, stream>>>(xc, Wo, bo, out);
    }
}

// Round 12
// 187.061 us; speedup vs baseline: 1.0529x; 1.0529x over previous
//
#include <hip/hip_runtime.h>
#include <hip/hip_bf16.h>

typedef __hip_bfloat16 bf16;
typedef short v8s __attribute__((ext_vector_type(8)));
typedef float v4f __attribute__((ext_vector_type(4)));
typedef float v16f __attribute__((ext_vector_type(16)));

#define S_ 2048
#define D_ 1024
#define H_ 16
#define HD_ 64

#define EXP2F(x) __builtin_amdgcn_exp2f(x)   /* v_exp_f32: 2^x on gfx950 */
#define NEG_BIG (-1.0e30f)
#define C2 0.1803368801111244f   /* (1/sqrt(64)) * log2(e), folded into Q */

#define GLDS16(g, l) __builtin_amdgcn_global_load_lds(                        \
    (const __attribute__((address_space(1))) unsigned int*)(g),               \
    (__attribute__((address_space(3))) unsigned int*)(l), 16, 0, 0)

#define CVT_PK(d, lo, hi) \
    asm("v_cvt_pk_bf16_f32 %0, %1, %2" : "=v"(d) : "v"(lo), "v"(hi))

/* exchanges high 32 lanes of a with low 32 lanes of b (gfx950) */
#define SWAPHALF(a, b) \
    asm("v_permlane32_swap_b32 %0, %1" : "+v"(a), "+v"(b))

#define MFMA32(a, b, c) __builtin_amdgcn_mfma_f32_32x32x16_bf16(a, b, c, 0, 0, 0)

static __device__ __forceinline__ unsigned short bf16_bits(bf16 h) {
    union { bf16 h; unsigned short u; } c; c.h = h; return c.u;
}

static __device__ __forceinline__ v8s pack_bf16x8(const float4 a, const float4 b) {
    union { v8s v; unsigned short u[8]; } r;
    r.u[0] = bf16_bits(__float2bfloat16(a.x));
    r.u[1] = bf16_bits(__float2bfloat16(a.y));
    r.u[2] = bf16_bits(__float2bfloat16(a.z));
    r.u[3] = bf16_bits(__float2bfloat16(a.w));
    r.u[4] = bf16_bits(__float2bfloat16(b.x));
    r.u[5] = bf16_bits(__float2bfloat16(b.y));
    r.u[6] = bf16_bits(__float2bfloat16(b.z));
    r.u[7] = bf16_bits(__float2bfloat16(b.w));
    return r.v;
}

// ---------------------------------------------------------------------------
// fp32 -> bf16 conversion pre-pass
// ---------------------------------------------------------------------------
__global__ __launch_bounds__(256)
void cvt_bf16(const float* __restrict__ x,  const float* __restrict__ wq,
              const float* __restrict__ wk, const float* __restrict__ wv,
              const float* __restrict__ wo,
              bf16* __restrict__ xb,  bf16* __restrict__ wqb,
              bf16* __restrict__ wkb, bf16* __restrict__ wvb,
              bf16* __restrict__ wob)
{
    const int seg = blockIdx.y;
    const float* src; bf16* dst; int n;
    switch (seg) {
        case 0: src = x;  dst = xb;  n = 4096 * 1024; break;
        case 1: src = wq; dst = wqb; n = 1024 * 1024; break;
        case 2: src = wk; dst = wkb; n = 1024 * 1024; break;
        case 3: src = wv; dst = wvb; n = 1024 * 1024; break;
        default:src = wo; dst = wob; n = 1024 * 1024; break;
    }
    const int idx = (blockIdx.x * 256 + threadIdx.x) * 8;
    if (idx >= n) return;
    *(v8s*)&dst[idx] = pack_bf16x8(*(const float4*)&src[idx],
                                   *(const float4*)&src[idx + 4]);
}

// ---------------------------------------------------------------------------
// QKV GEMM, 256x256 8-phase schedule (T3+T4+T5) + T2 XOR-swizzled LDS.
// (Verified round 4: T2 on the 8-phase structure gave ~-11us vs linear LDS.)
// ---------------------------------------------------------------------------
static __device__ __forceinline__ void stage_half(bf16* ldsbase, const bf16* gbase,
                                                  int w, int l) {
    const int r = l >> 3, c = ((l & 7) ^ r) * 8;  // T2 inverse-swizzled source
    GLDS16(gbase + (size_t)((2 * w + 0) * 8 + r) * 1024 + c, ldsbase + (2 * w + 0) * 512);
    GLDS16(gbase + (size_t)((2 * w + 1) * 8 + r) * 1024 + c, ldsbase + (2 * w + 1) * 512);
}

#define MF16(a, b, c) __builtin_amdgcn_mfma_f32_16x16x32_bf16(a, b, c, 0, 0, 0)

#define LDA(buf, mf0) { _Pragma("unroll") for (int m_ = 0; m_ < 4; ++m_) {          \
    af[m_][0] = *(const v8s*)&AsS[(buf)*16384 + abase + ((mf0) + m_)*1024 + sw0];   \
    af[m_][1] = *(const v8s*)&AsS[(buf)*16384 + abase + ((mf0) + m_)*1024 + sw1]; } }
#define LDB0(buf) { _Pragma("unroll") for (int n_ = 0; n_ < 2; ++n_) {              \
    b0f[n_][0] = *(const v8s*)&BsS[(buf)*16384 + bbase + n_*1024 + sw0];            \
    b0f[n_][1] = *(const v8s*)&BsS[(buf)*16384 + bbase + n_*1024 + sw1]; } }
#define LDB1(buf) { _Pragma("unroll") for (int n_ = 0; n_ < 2; ++n_) {              \
    b1f[n_][0] = *(const v8s*)&BsS[(buf)*16384 + bbase + (2 + n_)*1024 + sw0];      \
    b1f[n_][1] = *(const v8s*)&BsS[(buf)*16384 + bbase + (2 + n_)*1024 + sw1]; } }
#define MMQ(MH, NH, AF, BF) { _Pragma("unroll") for (int m_ = 0; m_ < 4; ++m_)      \
    _Pragma("unroll") for (int n_ = 0; n_ < 2; ++n_) {                              \
      acc[(MH)*4 + m_][(NH)*2 + n_] =                                               \
        MF16(AF[m_][0], BF[n_][0], acc[(MH)*4 + m_][(NH)*2 + n_]);                  \
      acc[(MH)*4 + m_][(NH)*2 + n_] =                                               \
        MF16(AF[m_][1], BF[n_][1], acc[(MH)*4 + m_][(NH)*2 + n_]); } }
#define BAR() __builtin_amdgcn_s_barrier()
#define VMC2() asm volatile("s_waitcnt vmcnt(2)" ::: "memory")
#define PRIO1() __builtin_amdgcn_s_setprio(1)
#define PRIO0() __builtin_amdgcn_s_setprio(0)

__global__ __launch_bounds__(512, 2)
void gemm_qkv_8p(const bf16* __restrict__ xb, const bf16* __restrict__ wqb,
                 const bf16* __restrict__ wkb, const bf16* __restrict__ wvb,
                 bf16* __restrict__ qd, bf16* __restrict__ kd, bf16* __restrict__ vtd)
{
    __shared__ bf16 AsS[2 * 16384];          // [buf][half 128][64]
    __shared__ bf16 BsS[2 * 16384];
    const int mode = blockIdx.z;
    const bf16* __restrict__ W = (mode == 0) ? wqb : (mode == 1) ? wkb : wvb;
    const int m0 = blockIdx.x * 256;
    const int n0 = blockIdx.y * 256;
    const int t = threadIdx.x;
    const int lane = t & 63, w = t >> 6;
    const int wr = w >> 2, wc = w & 3;       // 2M x 4N waves
    const int l15 = lane & 15, quad = lane >> 4;
    const int sw0 = (quad ^ (l15 & 7)) * 8;          // T2 swizzled col-slots
    const int sw1 = ((quad + 4) ^ (l15 & 7)) * 8;
    const int abase = wr * 8192 + l15 * 64;
    const int bbase = (wc >> 1) * 8192 + (wc & 1) * 4096 + l15 * 64;
    const bf16* Aap = xb + (size_t)m0 * 1024;
    const bf16* Bbp = W + (size_t)n0 * 1024;

    v4f acc[8][4] = {};
    v8s af[4][2], b0f[2][2], b1f[2][2];

    // prologue: tile0 (buf0, 4 halves) + tile1 A0 (buf1); keep tile1-A0 in flight
    stage_half(AsS,          Aap,          w, lane);
    stage_half(AsS + 8192,   Aap + 131072, w, lane);
    stage_half(BsS,          Bbp,          w, lane);
    stage_half(BsS + 8192,   Bbp + 131072, w, lane);
    stage_half(AsS + 16384,  Aap + 64,     w, lane);
    VMC2();
    BAR();

    for (int i = 0; i < 8; ++i) {
        const int kc = i * 128;
        // ph1: buf0 A-mh0 + B-nh0; stage tile(2i+1) A1 -> buf1
        LDA(0, 0); LDB0(0);
        stage_half(AsS + 16384 + 8192, Aap + 131072 + kc + 64, w, lane);
        BAR(); PRIO1(); MMQ(0, 0, af, b0f); PRIO0(); BAR();
        // ph2: buf0 B-nh1; stage tile(2i+1) B0 -> buf1
        LDB1(0);
        stage_half(BsS + 16384, Bbp + kc + 64, w, lane);
        BAR(); PRIO1(); MMQ(0, 1, af, b1f); PRIO0(); BAR();
        // ph3: buf0 A-mh1; stage tile(2i+1) B1 -> buf1
        LDA(0, 4);
        stage_half(BsS + 16384 + 8192, Bbp + 131072 + kc + 64, w, lane);
        BAR(); PRIO1(); MMQ(1, 1, af, b1f); PRIO0(); BAR();
        // ph4: stage tile(2i+2) A0 -> buf0; counted wait for tile(2i+1)
        stage_half(AsS, Aap + kc + 128, w, lane);
        VMC2();
        BAR(); PRIO1(); MMQ(1, 0, af, b0f); PRIO0(); BAR();
        // ph5: buf1 A-mh0 + B-nh0; stage tile(2i+2) A1 -> buf0
        LDA(1, 0); LDB0(1);
        stage_half(AsS + 8192, Aap + 131072 + kc + 128, w, lane);
        BAR(); PRIO1(); MMQ(0, 0, af, b0f); PRIO0(); BAR();
        // ph6: buf1 B-nh1; stage tile(2i+2) B0 -> buf0
        LDB1(1);
        stage_half(BsS, Bbp + kc + 128, w, lane);
        BAR(); PRIO1(); MMQ(0, 1, af, b1f); PRIO0(); BAR();
        // ph7: buf1 A-mh1; stage tile(2i+2) B1 -> buf0
        LDA(1, 4);
        stage_half(BsS + 8192, Bbp + 131072 + kc + 128, w, lane);
        BAR(); PRIO1(); MMQ(1, 1, af, b1f); PRIO0(); BAR();
        // ph8: stage tile(2i+3) A0 -> buf1; counted wait for tile(2i+2)
        stage_half(AsS + 16384, Aap + kc + 192, w, lane);
        VMC2();
        BAR(); PRIO1(); MMQ(1, 0, af, b0f); PRIO0(); BAR();
    }

    const float qscale = (mode == 0) ? C2 : 1.0f;
#pragma unroll
    for (int mf = 0; mf < 8; ++mf) {
        const int mb = m0 + wr * 128 + mf * 16 + quad * 4;
        const int b_ = mb >> 11, s = mb & 2047;
#pragma unroll
        for (int nf = 0; nf < 4; ++nf) {
            const int n = n0 + wc * 64 + nf * 16 + l15;
            const int h = n >> 6, d = n & 63;
            if (mode == 2) {
                unsigned int lo = (unsigned int)bf16_bits(__float2bfloat16(acc[mf][nf][0]))
                                | ((unsigned int)bf16_bits(__float2bfloat16(acc[mf][nf][1])) << 16);
                unsigned int hi = (unsigned int)bf16_bits(__float2bfloat16(acc[mf][nf][2]))
                                | ((unsigned int)bf16_bits(__float2bfloat16(acc[mf][nf][3])) << 16);
                uint2 pv; pv.x = lo; pv.y = hi;
                *(uint2*)&vtd[((b_ * H_ + h) * HD_ + d) * S_ + s] = pv;
            } else {
                bf16* __restrict__ dst = (mode == 0) ? qd : kd;
#pragma unroll
                for (int r = 0; r < 4; ++r)
                    dst[((b_ * H_ + h) * S_ + (s + r)) * HD_ + d] =
                        __float2bfloat16(acc[mf][nf][r] * qscale);
            }
        }
    }
}

// ---------------------------------------------------------------------------
// Output GEMM (m97-style 128x128): 256 blocks keeps all CUs busy at N=1024.
// ---------------------------------------------------------------------------
__global__ __launch_bounds__(256)
void gemm_out_f(const bf16* __restrict__ ctx, const bf16* __restrict__ wob,
                const float* __restrict__ bo, float* __restrict__ out)
{
    const int m0 = blockIdx.x * 128;
    const int n0 = blockIdx.y * 128;
    __shared__ bf16 As[128 * 32];
    __shared__ bf16 Bs[128 * 32];
    const int t    = threadIdx.x;
    const int lane = t & 63, w = t >> 6;
    const int wr = w >> 1, wc = w & 1;
    const int l15 = lane & 15, quad = lane >> 4;
    const int r16 = lane >> 2, c8 = (lane & 3) * 8;
    v4f acc[4][4] = {};

    const bf16* ga = &ctx[(m0 + w*16 + r16) * 1024 + c8];
    const bf16* gb = &wob[(n0 + w*16 + r16) * 1024 + c8];
    bf16* la0 = &As[w * 16 * 32];
    bf16* la1 = &As[(64 + w * 16) * 32];
    bf16* lb0 = &Bs[w * 16 * 32];
    bf16* lb1 = &Bs[(64 + w * 16) * 32];

    for (int k0 = 0; k0 < 1024; k0 += 32) {
        __syncthreads();
        GLDS16(ga + k0,             la0);
        GLDS16(ga + k0 + 64 * 1024, la1);
        GLDS16(gb + k0,             lb0);
        GLDS16(gb + k0 + 64 * 1024, lb1);
        __syncthreads();
        v8s a[4], b[4];
#pragma unroll
        for (int mt = 0; mt < 4; mt++) a[mt] = *(const v8s*)&As[(wr*64 + mt*16 + l15)*32 + quad*8];
#pragma unroll
        for (int nt = 0; nt < 4; nt++) b[nt] = *(const v8s*)&Bs[(wc*64 + nt*16 + l15)*32 + quad*8];
#pragma unroll
        for (int mt = 0; mt < 4; mt++)
#pragma unroll
            for (int nt = 0; nt < 4; nt++)
                acc[mt][nt] = __builtin_amdgcn_mfma_f32_16x16x32_bf16(a[mt], b[nt], acc[mt][nt], 0, 0, 0);
    }

#pragma unroll
    for (int mt = 0; mt < 4; mt++) {
        const int mb = m0 + wr*64 + mt*16 + quad*4;
#pragma unroll
        for (int nt = 0; nt < 4; nt++) {
            const int n = n0 + wc*64 + nt*16 + l15;
            const float bias = bo[n];
#pragma unroll
            for (int r = 0; r < 4; r++)
                out[(mb + r)*1024 + n] = acc[mt][nt][r] + bias;
        }
    }
}

// ---------------------------------------------------------------------------
// FALLBACK GEMMs (fp32 inputs, cvt fused in staging)
// ---------------------------------------------------------------------------
__global__ __launch_bounds__(256)
void gemm_qkv(const float* __restrict__ x, const float* __restrict__ Wq,
              const float* __restrict__ Wk, const float* __restrict__ Wv,
              bf16* __restrict__ qd, bf16* __restrict__ kd, bf16* __restrict__ vtd)
{
    const int mode = blockIdx.z;
    const float* __restrict__ W = (mode == 0) ? Wq : (mode == 1) ? Wk : Wv;
    const int m0 = blockIdx.x * 128;
    const int n0 = blockIdx.y * 128;
    __shared__ bf16 As[128 * 40];
    __shared__ bf16 Bs[128 * 40];
    const int t    = threadIdx.x;
    const int lane = t & 63, w = t >> 6;
    const int wr = w >> 1, wc = w & 1;
    const int l15 = lane & 15, quad = lane >> 4;
    const int srow = t >> 2, scol = (t & 3) * 8;
    v4f acc[4][4] = {};

    for (int k0 = 0; k0 < 1024; k0 += 32) {
        __syncthreads();
        {
            const float* pa = &x[(m0 + srow) * 1024 + k0 + scol];
            *(v8s*)&As[srow*40 + scol] = pack_bf16x8(*(const float4*)pa, *(const float4*)(pa + 4));
            const float* pa2 = pa + 64 * 1024;
            *(v8s*)&As[(srow+64)*40 + scol] = pack_bf16x8(*(const float4*)pa2, *(const float4*)(pa2 + 4));
            const float* pb = &W[(n0 + srow) * 1024 + k0 + scol];
            *(v8s*)&Bs[srow*40 + scol] = pack_bf16x8(*(const float4*)pb, *(const float4*)(pb + 4));
            const float* pb2 = pb + 64 * 1024;
            *(v8s*)&Bs[(srow+64)*40 + scol] = pack_bf16x8(*(const float4*)pb2, *(const float4*)(pb2 + 4));
        }
        __syncthreads();
        v8s a[4], b[4];
#pragma unroll
        for (int mt = 0; mt < 4; mt++) a[mt] = *(const v8s*)&As[(wr*64 + mt*16 + l15)*40 + quad*8];
#pragma unroll
        for (int nt = 0; nt < 4; nt++) b[nt] = *(const v8s*)&Bs[(wc*64 + nt*16 + l15)*40 + quad*8];
#pragma unroll
        for (int mt = 0; mt < 4; mt++)
#pragma unroll
            for (int nt = 0; nt < 4; nt++)
                acc[mt][nt] = __builtin_amdgcn_mfma_f32_16x16x32_bf16(a[mt], b[nt], acc[mt][nt], 0, 0, 0);
    }

    const float qscale = (mode == 0) ? C2 : 1.0f;
#pragma unroll
    for (int mt = 0; mt < 4; mt++) {
        const int mb = m0 + wr*64 + mt*16 + quad*4;
        const int b_ = mb >> 11, s = mb & 2047;
#pragma unroll
        for (int nt = 0; nt < 4; nt++) {
            const int n = n0 + wc*64 + nt*16 + l15;
            const int h = n >> 6, d = n & 63;
            if (mode == 2) {
                unsigned int lo = (unsigned int)bf16_bits(__float2bfloat16(acc[mt][nt][0]))
                                | ((unsigned int)bf16_bits(__float2bfloat16(acc[mt][nt][1])) << 16);
                unsigned int hi = (unsigned int)bf16_bits(__float2bfloat16(acc[mt][nt][2]))
                                | ((unsigned int)bf16_bits(__float2bfloat16(acc[mt][nt][3])) << 16);
                uint2 pv; pv.x = lo; pv.y = hi;
                *(uint2*)&vtd[((b_*H_ + h)*HD_ + d)*S_ + s] = pv;
            } else {
                bf16* __restrict__ dst = (mode == 0) ? qd : kd;
#pragma unroll
                for (int r = 0; r < 4; r++)
                    dst[((b_*H_ + h)*S_ + (s + r))*HD_ + d] = __float2bfloat16(acc[mt][nt][r] * qscale);
            }
        }
    }
}

__global__ __launch_bounds__(256)
void gemm_out(const bf16* __restrict__ ctx, const float* __restrict__ Wo,
              const float* __restrict__ bo, float* __restrict__ out)
{
    const int m0 = blockIdx.x * 128;
    const int n0 = blockIdx.y * 128;
    __shared__ bf16 As[128 * 40];
    __shared__ bf16 Bs[128 * 40];
    const int t    = threadIdx.x;
    const int lane = t & 63, w = t >> 6;
    const int wr = w >> 1, wc = w & 1;
    const int l15 = lane & 15, quad = lane >> 4;
    const int srow = t >> 2, scol = (t & 3) * 8;
    v4f acc[4][4] = {};

    for (int k0 = 0; k0 < 1024; k0 += 32) {
        __syncthreads();
        {
            *(v8s*)&As[srow*40 + scol]      = *(const v8s*)&ctx[(m0+srow)*1024 + k0 + scol];
            *(v8s*)&As[(srow+64)*40 + scol] = *(const v8s*)&ctx[(m0+srow+64)*1024 + k0 + scol];
            const float* pb = &Wo[(n0 + srow) * 1024 + k0 + scol];
            *(v8s*)&Bs[srow*40 + scol] = pack_bf16x8(*(const float4*)pb, *(const float4*)(pb + 4));
            const float* pb2 = pb + 64 * 1024;
            *(v8s*)&Bs[(srow+64)*40 + scol] = pack_bf16x8(*(const float4*)pb2, *(const float4*)(pb2 + 4));
        }
        __syncthreads();
        v8s a[4], b[4];
#pragma unroll
        for (int mt = 0; mt < 4; mt++) a[mt] = *(const v8s*)&As[(wr*64 + mt*16 + l15)*40 + quad*8];
#pragma unroll
        for (int nt = 0; nt < 4; nt++) b[nt] = *(const v8s*)&Bs[(wc*64 + nt*16 + l15)*40 + quad*8];
#pragma unroll
        for (int mt = 0; mt < 4; mt++)
#pragma unroll
            for (int nt = 0; nt < 4; nt++)
                acc[mt][nt] = __builtin_amdgcn_mfma_f32_16x16x32_bf16(a[mt], b[nt], acc[mt][nt], 0, 0, 0);
    }

#pragma unroll
    for (int mt = 0; mt < 4; mt++) {
        const int mb = m0 + wr*64 + mt*16 + quad*4;
#pragma unroll
        for (int nt = 0; nt < 4; nt++) {
            const int n = n0 + wc*64 + nt*16 + l15;
            const float bias = bo[n];
#pragma unroll
            for (int r = 0; r < 4; r++)
                out[(mb + r)*1024 + n] = acc[mt][nt][r] + bias;
        }
    }
}

// ---------------------------------------------------------------------------
// Causal flash attention v11 (verified best: 48-49us, total 187.8-189.2us):
//  * 8 waves = 2 sides x 4 waves; each wave owns 32 q-rows (side = 128).
//    Uniform pairing (p, 15-p) = constant 34 tile-units/block (the load
//    balancer — R10's un-paired variant lost 9us to imbalance), KVBLK=128,
//    V double-buffer, 1 barrier/tile.
//  * QK^T computed swapped (mfma_32x32x16(K, Q)): lane holds P column q=l31;
//    P->bf16 A-fragments rebuilt with 8x v_cvt_pk_bf16_f32 + 4x
//    v_permlane32_swap_b32 per 32-col group -> NO P LDS round-trip (T12).
//  * K direct from global with consume-then-prefetch chain.
//  * V fragments from LDS as 32x32 B-operands (b128, row = l31 / l31+32).
//  Session ledger: v8 (16q/wave), v9 (zero-LDS 1-wave), v12 (split-KV),
//  v13 (un-paired) all regressed — this geometry is the verified optimum.
// ---------------------------------------------------------------------------
#define SOFTMAX_PV(sa, ks0, vA0, vA1, vB0, vB1)                                \
    {                                                                          \
        const bool full_ = ((ks0) + 31 <= q0w);                                \
        if (full_) {                                                           \
            _Pragma("unroll")                                                  \
            for (int r = 0; r < 16; r++) {                                     \
                const float p = EXP2F(sa[r]); sa[r] = p;                       \
                if (r & 1) ps1 += p; else ps0 += p;                            \
            }                                                                  \
        } else {                                                               \
            const int kb_ = (ks0) + 4 * hi - q0w - l31;                        \
            _Pragma("unroll")                                                  \
            for (int r = 0; r < 16; r++) {                                     \
                const int kl_ = (r & 3) + 8 * (r >> 2);                        \
                const float p = EXP2F((kb_ + kl_ <= 0) ? sa[r] : NEG_BIG);     \
                sa[r] = p;                                                     \
                if (r & 1) ps1 += p; else ps0 += p;                            \
            }                                                                  \
        }                                                                      \
        unsigned u0, u1, u2, u3, u4, u5, u6, u7;                               \
        CVT_PK(u0, sa[0],  sa[1]);  CVT_PK(u1, sa[2],  sa[3]);                 \
        CVT_PK(u2, sa[4],  sa[5]);  CVT_PK(u3, sa[6],  sa[7]);                 \
        CVT_PK(u4, sa[8],  sa[9]);  CVT_PK(u5, sa[10], sa[11]);                \
        CVT_PK(u6, sa[12], sa[13]); CVT_PK(u7, sa[14], sa[15]);                \
        SWAPHALF(u0, u2); SWAPHALF(u1, u3);                                    \
        SWAPHALF(u4, u6); SWAPHALF(u5, u7);                                    \
        union { v8s v; unsigned w[4]; } pa0_, pa1_;                            \
        pa0_.w[0] = u0; pa0_.w[1] = u1; pa0_.w[2] = u2; pa0_.w[3] = u3;        \
        pa1_.w[0] = u4; pa1_.w[1] = u5; pa1_.w[2] = u6; pa1_.w[3] = u7;        \
        o0 = MFMA32(pa0_.v, vA0, o0);                                          \
        o1 = MFMA32(pa0_.v, vB0, o1);                                          \
        o0 = MFMA32(pa1_.v, vA1, o0);                                          \
        o1 = MFMA32(pa1_.v, vB1, o1);                                          \
    }

__global__ __launch_bounds__(512)
void flash_attn(const bf16* __restrict__ qd, const bf16* __restrict__ kd,
                const bf16* __restrict__ vtd, bf16* __restrict__ ctx)
{
    const int bh = blockIdx.x;            // 0..31 — same bh => same XCD
    const int p  = blockIdx.y;            // 0..7: block owns q-tiles p and 15-p
    const int t = threadIdx.x;            // 0..511
    const int lane = t & 63, w = t >> 6;  // 8 waves
    const int l31 = lane & 31, hi = lane >> 5;
    const int side = w >> 2, wl = w & 3;  // side 0: tile p, side 1: tile 15-p
    const int q0w = (side ? (15 - p) : p) * 128 + wl * 32;   // wave's 32 q-rows
    const int nT = 16 - p;                // 128-wide kv tiles (longer side)

    __shared__ bf16 Vs[2][64 * 136];      // [d][kv 128 + 8 pad]

    // Q B-frags (col=q=l31, k-elem=d=hi*8+j+16*c), resident whole kernel
    const bf16* qp = qd + ((size_t)bh * S_ + q0w + l31) * HD_ + hi * 8;
    const v8s qf0 = *(const v8s*)(qp);
    const v8s qf1 = *(const v8s*)(qp + 16);
    const v8s qf2 = *(const v8s*)(qp + 32);
    const v8s qf3 = *(const v8s*)(qp + 48);

    v16f o0 = {}, o1 = {};                // d = l31 / l31+32; q via regs
    float ps0 = 0.f, ps1 = 0.f;

    // V staging: thread covers (d = t>>3, kv = (t&7)*8) and (.., kv+64)
    const int vrow = t >> 3, vcol = (t & 7) * 8;
    const bf16* vp = vtd + ((size_t)bh * HD_ + vrow) * S_ + vcol;
    v8s pv0 = *(const v8s*)vp;
    v8s pv1 = *(const v8s*)(vp + 64);

    // K A-frags (row=k=l31 (+32 for B-group), k-elem=d), group 0
    const bf16* kq = kd + ((size_t)bh * S_ + l31) * HD_ + hi * 8;
    v8s kA0 = *(const v8s*)(kq);
    v8s kA1 = *(const v8s*)(kq + 16);
    v8s kA2 = *(const v8s*)(kq + 32);
    v8s kA3 = *(const v8s*)(kq + 48);
    v8s kB0 = *(const v8s*)(kq + 32 * HD_);
    v8s kB1 = *(const v8s*)(kq + 32 * HD_ + 16);
    v8s kB2 = *(const v8s*)(kq + 32 * HD_ + 32);
    v8s kB3 = *(const v8s*)(kq + 32 * HD_ + 48);

    for (int it = 0; it < nT; ++it) {
        const int c0 = it * 128;
        bf16* Vb = &Vs[it & 1][0];
        *(v8s*)&Vb[vrow*136 + vcol]      = pv0;
        *(v8s*)&Vb[vrow*136 + 64 + vcol] = pv1;
        __syncthreads();
        vp += 128;
        pv0 = *(const v8s*)vp;            // prefetch next V tile (overrun stays in ws)
        pv1 = *(const v8s*)(vp + 64);

#pragma unroll
        for (int h = 0; h < 2; ++h) {
            const int ch = c0 + h * 64;
            const bool actA = (ch      <= q0w + 31);
            const bool actB = (ch + 32 <= q0w + 31);
            const bool nact = (ch + 64 <= q0w + 31);

            v16f sa0 = {}, sa1 = {};
            if (actA) {
                sa0 = MFMA32(kA0, qf0, sa0);
                sa0 = MFMA32(kA1, qf1, sa0);
                sa0 = MFMA32(kA2, qf2, sa0);
                sa0 = MFMA32(kA3, qf3, sa0);
            }
            if (actB) {
                sa1 = MFMA32(kB0, qf0, sa1);
                sa1 = MFMA32(kB1, qf1, sa1);
                sa1 = MFMA32(kB2, qf2, sa1);
                sa1 = MFMA32(kB3, qf3, sa1);
            }

            // K consumed -> prefetch next 64-group into the same registers
            if (nact) {
                const bf16* kn = kq + (size_t)(ch + 64) * HD_;
                kA0 = *(const v8s*)(kn);
                kA1 = *(const v8s*)(kn + 16);
                kA2 = *(const v8s*)(kn + 32);
                kA3 = *(const v8s*)(kn + 48);
                kB0 = *(const v8s*)(kn + 32 * HD_);
                kB1 = *(const v8s*)(kn + 32 * HD_ + 16);
                kB2 = *(const v8s*)(kn + 32 * HD_ + 32);
                kB3 = *(const v8s*)(kn + 32 * HD_ + 48);
            }

            if (actA) {
                const int kb = h * 64;
                const v8s vA0 = *(const v8s*)&Vb[ l31      *136 + kb      + hi*8];
                const v8s vA1 = *(const v8s*)&Vb[ l31      *136 + kb + 16 + hi*8];
                const v8s vB0 = *(const v8s*)&Vb[(l31 + 32)*136 + kb      + hi*8];
                const v8s vB1 = *(const v8s*)&Vb[(l31 + 32)*136 + kb + 16 + hi*8];
                SOFTMAX_PV(sa0, ch, vA0, vA1, vB0, vB1);
            }
            if (actB) {
                const int kb = h * 64 + 32;
                const v8s vA2 = *(const v8s*)&Vb[ l31      *136 + kb      + hi*8];
                const v8s vA3 = *(const v8s*)&Vb[ l31      *136 + kb + 16 + hi*8];
                const v8s vB2 = *(const v8s*)&Vb[(l31 + 32)*136 + kb      + hi*8];
                const v8s vB3 = *(const v8s*)&Vb[(l31 + 32)*136 + kb + 16 + hi*8];
                SOFTMAX_PV(sa1, ch + 32, vA2, vA3, vB2, vB3);
            }
        }
    }

    // denominator for q=l31: this lane's half + the other hi half
    const float ps = ps0 + ps1;
    const float tot = ps + __shfl_xor(ps, 32);
    const int b_ = bh >> 4, hh = bh & 15;
    bf16* cb = ctx + ((size_t)b_ * S_ + q0w) * D_ + hh * HD_ + l31;
#pragma unroll
    for (int r = 0; r < 16; r++) {
        const int qr = (r & 3) + 8 * (r >> 2) + 4 * hi;
        const float linv = 1.0f / __shfl(tot, qr);
        cb[(size_t)qr * D_]      = __float2bfloat16(o0[r] * linv);
        cb[(size_t)qr * D_ + 32] = __float2bfloat16(o1[r] * linv);
    }
}

extern "C" void kernel_launch(void* const* d_in, const int* in_sizes, int n_in,
                              void* d_out, int out_size, void* d_ws, size_t ws_size,
                              hipStream_t stream) {
    const float* x  = (const float*)d_in[0];
    const float* Wq = (const float*)d_in[1];
    const float* Wk = (const float*)d_in[2];
    const float* Wv = (const float*)d_in[3];
    const float* Wo = (const float*)d_in[4];
    const float* bo = (const float*)d_in[5];
    float* out = (float*)d_out;

    const size_t SEG = (size_t)2 * H_ * S_ * HD_;      // 4 Mi bf16 elems = 8 MB
    bf16* qd  = (bf16*)d_ws;
    bf16* kd  = qd  + SEG;
    bf16* vtd = kd  + SEG;
    bf16* xc  = vtd + SEG;                             // x-bf16, later ctx
    bf16* wqb = xc + SEG;
    bf16* wkb = wqb + 1024 * 1024;
    bf16* wvb = wkb + 1024 * 1024;
    bf16* wob = wvb + 1024 * 1024;

    const size_t need_fast = (4 * SEG + 4 * 1024 * 1024) * sizeof(bf16);   // 40 MB

    if (ws_size >= need_fast) {
        cvt_bf16<<<dim3(2048, 5), 256, 0, stream>>>(x, Wq, Wk, Wv, Wo,
                                                    xc, wqb, wkb, wvb, wob);
        gemm_qkv_8p<<<dim3(16, 4, 3), 512, 0, stream>>>(xc, wqb, wkb, wvb, qd, kd, vtd);
        flash_attn<<<dim3(32, 8), 512, 0, stream>>>(qd, kd, vtd, xc);   // xc = ctx
        gemm_out_f<<<dim3(32, 8), 256, 0, stream>>>(xc, wob, bo, out);
    } else {
        gemm_qkv<<<dim3(32, 8, 3), 256, 0, stream>>>(x, Wq, Wk, Wv, qd, kd, vtd);
        flash_attn<<<dim3(32, 8), 512, 0, stream>>>(qd, kd, vtd, xc);
        gemm_out<<<dim3(32, 8), 256, 0, stream>>>(xc, Wo, bo, out);
    }
}